// Round 12
// baseline (276.629 us; speedup 1.0000x reference)
//
#include <hip/hip_runtime.h>
#include <hip/hip_bf16.h>

// GCN 3-layer forward on MI355X.  (R10 base; fused64 -> 4-way split gather)
// h' = bf16( dinv .* (x @ W) );  out = relu(dinv .* (h'[i]+sum h'[src]) + b)
// CSR via single-pass bucket binning (arena slots).
// fused64: 32 lanes/node (8 col-lanes x 4 quarter-streams, shfl_xor join)
//   -> ~1-2 serialized latency rounds per wave (was ~3).
// fused32: R7 form (8 lanes/node) -- R11 showed its split variant regresses.

#define BLOCK 256
#define NBUCKET 512
#define CHUNK 4096
#define SLOT 4608
#define MAX_NPB 256

typedef float f32x4 __attribute__((ext_vector_type(4)));

__device__ __forceinline__ float4 fma4(float s, float4 a, float4 b) {
  return make_float4(fmaf(s, a.x, b.x), fmaf(s, a.y, b.y),
                     fmaf(s, a.z, b.z), fmaf(s, a.w, b.w));
}

__device__ __forceinline__ unsigned int bf16r(float f) {
  unsigned int u = __float_as_uint(f);
  u += 0x7fffu + ((u >> 16) & 1u);
  return u >> 16;
}

__device__ __forceinline__ void acc_bf8(float4& lo, float4& hi, uint4 u) {
  lo.x += __uint_as_float(u.x << 16);
  lo.y += __uint_as_float(u.x & 0xffff0000u);
  lo.z += __uint_as_float(u.y << 16);
  lo.w += __uint_as_float(u.y & 0xffff0000u);
  hi.x += __uint_as_float(u.z << 16);
  hi.y += __uint_as_float(u.z & 0xffff0000u);
  hi.z += __uint_as_float(u.w << 16);
  hi.w += __uint_as_float(u.w & 0xffff0000u);
}

// ---- CSR build ----

__global__ __launch_bounds__(BLOCK) void binning_kernel(
    const int* __restrict__ src, const int* __restrict__ dst,
    int* __restrict__ bcursor, int* __restrict__ binned, int e, int npb) {
  __shared__ int h[NBUCKET];
  __shared__ int base[NBUCKET];
  for (int i = threadIdx.x; i < NBUCKET; i += BLOCK) h[i] = 0;
  __syncthreads();
  const int cbase = blockIdx.x * CHUNK;
#pragma unroll
  for (int k = 0; k < CHUNK; k += BLOCK * 4) {
    int i = cbase + k + threadIdx.x * 4;
    if (i + 3 < e) {
      int4 d4 = *(const int4*)(dst + i);
      atomicAdd(&h[d4.x / npb], 1);
      atomicAdd(&h[d4.y / npb], 1);
      atomicAdd(&h[d4.z / npb], 1);
      atomicAdd(&h[d4.w / npb], 1);
    } else {
      for (int t = 0; t < 4; ++t)
        if (i + t < e) atomicAdd(&h[dst[i + t] / npb], 1);
    }
  }
  __syncthreads();
  for (int i = threadIdx.x; i < NBUCKET; i += BLOCK) {
    int c = h[i];
    base[i] = c ? atomicAdd(&bcursor[i], c) : 0;
    h[i] = 0;
  }
  __syncthreads();
#pragma unroll
  for (int k = 0; k < CHUNK; k += BLOCK * 4) {
    int i = cbase + k + threadIdx.x * 4;
    if (i + 3 < e) {
      int4 d4 = *(const int4*)(dst + i);
      int4 s4 = *(const int4*)(src + i);
      int b0 = d4.x / npb, b1 = d4.y / npb, b2 = d4.z / npb, b3 = d4.w / npb;
      int o0 = atomicAdd(&h[b0], 1);
      int o1 = atomicAdd(&h[b1], 1);
      int o2 = atomicAdd(&h[b2], 1);
      int o3 = atomicAdd(&h[b3], 1);
      binned[b0 * SLOT + base[b0] + o0] = s4.x | ((d4.x - b0 * npb) << 17);
      binned[b1 * SLOT + base[b1] + o1] = s4.y | ((d4.y - b1 * npb) << 17);
      binned[b2 * SLOT + base[b2] + o2] = s4.z | ((d4.z - b2 * npb) << 17);
      binned[b3 * SLOT + base[b3] + o3] = s4.w | ((d4.w - b3 * npb) << 17);
    } else {
      for (int t = 0; t < 4; ++t) {
        if (i + t < e) {
          int d = dst[i + t];
          int bkt = d / npb;
          int lofs = atomicAdd(&h[bkt], 1);
          binned[bkt * SLOT + base[bkt] + lofs] =
              src[i + t] | ((d - bkt * npb) << 17);
        }
      }
    }
  }
}

__global__ __launch_bounds__(BLOCK) void bucket_build(
    const int* __restrict__ binned, const int* __restrict__ bcursor,
    int* __restrict__ offs, int* __restrict__ cnt, float* __restrict__ dinv,
    int* __restrict__ csr_src, int n, int npb) {
  __shared__ int nhist[MAX_NPB];
  __shared__ int noff[MAX_NPB];
  __shared__ int lcsr[SLOT];
  const int b = blockIdx.x;
  const int node_base = b * npb;
  const int nodes = min(npb, n - node_base);
  if (nodes <= 0) return;
  const int ebase = b * SLOT;
  const int ecnt = bcursor[b];
  for (int i = threadIdx.x; i < npb; i += BLOCK) nhist[i] = 0;
  __syncthreads();
  for (int i = threadIdx.x; i < ecnt; i += BLOCK)
    atomicAdd(&nhist[binned[ebase + i] >> 17], 1);
  __syncthreads();
  if (threadIdx.x < 64) {
    const int lane = threadIdx.x;
    const int bi = lane * 4;
    int v0 = (bi + 0 < nodes) ? nhist[bi + 0] : 0;
    int v1 = (bi + 1 < nodes) ? nhist[bi + 1] : 0;
    int v2 = (bi + 2 < nodes) ? nhist[bi + 2] : 0;
    int v3 = (bi + 3 < nodes) ? nhist[bi + 3] : 0;
    int tsum = v0 + v1 + v2 + v3;
    int s = tsum;
#pragma unroll
    for (int o = 1; o < 64; o <<= 1) {
      int u = __shfl_up(s, o, 64);
      if (lane >= o) s += u;
    }
    int texcl = s - tsum;
    if (bi + 0 < nodes) noff[bi + 0] = texcl;
    if (bi + 1 < nodes) noff[bi + 1] = texcl + v0;
    if (bi + 2 < nodes) noff[bi + 2] = texcl + v0 + v1;
    if (bi + 3 < nodes) noff[bi + 3] = texcl + v0 + v1 + v2;
  }
  __syncthreads();
  for (int i = threadIdx.x; i < nodes; i += BLOCK) {
    int c = nhist[i];
    offs[node_base + i] = ebase + noff[i];
    cnt[node_base + i] = c;
    dinv[node_base + i] = rsqrtf((float)(c + 1));
  }
  __syncthreads();
  for (int i = threadIdx.x; i < ecnt; i += BLOCK) {
    int v = binned[ebase + i];
    int pos = atomicAdd(&noff[v >> 17], 1);
    lcsr[pos] = v & 0x1ffff;
  }
  __syncthreads();
  for (int i = threadIdx.x; i < ecnt; i += BLOCK)
    csr_src[ebase + i] = lcsr[i];
}

// ---- dense layers ----

// Layer-1 GEMM: 1 row x 4 cols/thread, W in LDS.
__global__ __launch_bounds__(BLOCK) void gemm1_kernel(
    const float* __restrict__ x, const float* __restrict__ W,
    const float* __restrict__ dinv, unsigned short* __restrict__ hbf, int n) {
  __shared__ float Ws[64 * 64];
  for (int i = threadIdx.x * 4; i < 64 * 64; i += BLOCK * 4)
    *(float4*)(Ws + i) = *(const float4*)(W + i);
  __syncthreads();
  const int row = blockIdx.x * 16 + (int)(threadIdx.x >> 4);
  const int c4 = (threadIdx.x & 15) * 4;
  if (row >= n) return;
  const float* xr = x + (size_t)row * 64;
  float4 acc = make_float4(0.f, 0.f, 0.f, 0.f);
#pragma unroll
  for (int k = 0; k < 64; k += 4) {
    f32x4 xn = __builtin_nontemporal_load((const f32x4*)(xr + k));
    float4 w0 = *(const float4*)(Ws + (k + 0) * 64 + c4);
    float4 w1 = *(const float4*)(Ws + (k + 1) * 64 + c4);
    float4 w2 = *(const float4*)(Ws + (k + 2) * 64 + c4);
    float4 w3 = *(const float4*)(Ws + (k + 3) * 64 + c4);
    acc = fma4(xn.x, w0, acc);
    acc = fma4(xn.y, w1, acc);
    acc = fma4(xn.z, w2, acc);
    acc = fma4(xn.w, w3, acc);
  }
  float d = dinv[row];
  uint2 packed;
  packed.x = bf16r(d * acc.x) | (bf16r(d * acc.y) << 16);
  packed.y = bf16r(d * acc.z) | (bf16r(d * acc.w) << 16);
  *(uint2*)(hbf + (size_t)row * 64 + c4) = packed;
}

// Fused layer 1->2: agg (64, relu, b) -> gemm (64->64) -> bf16.
// 32 lanes/node = 8 col-lanes x 4 quarter-streams; 8 nodes/block.
__global__ __launch_bounds__(BLOCK) void fused_agg_gemm64(
    const unsigned short* __restrict__ hin, const int* __restrict__ csr_src,
    const int* __restrict__ offs, const int* __restrict__ cnt,
    const float* __restrict__ dinv, const float* __restrict__ bias,
    const float* __restrict__ Wn, unsigned short* __restrict__ hout, int n) {
  __shared__ float Ws[64 * 64];
  __shared__ float vrow[8][68];  // +4 pad
  for (int i = threadIdx.x * 4; i < 64 * 64; i += BLOCK * 4)
    *(float4*)(Ws + i) = *(const float4*)(Wn + i);
  __syncthreads();
  const int g = threadIdx.x >> 5;         // node within block (0..7)
  const int lane32 = threadIdx.x & 31;
  const int colgrp = lane32 & 7;
  const int quarter = lane32 >> 3;        // 0..3
  const int c8 = colgrp * 8;
  const int node = blockIdx.x * 8 + g;
  const bool valid = node < n;
  float dnode = 0.f;
  if (valid) {
    const int start = offs[node];
    const int cn = cnt[node];
    const unsigned short* hcol = hin + c8;
    float4 l0 = make_float4(0.f, 0.f, 0.f, 0.f), h0 = l0;
    float4 l1 = l0, h1 = l0, l2 = l0, h2 = l0, l3 = l0, h3 = l0;
    if (quarter == 0)
      acc_bf8(l0, h0, *(const uint4*)(hcol + (size_t)node * 64));  // self
    int j = quarter * 4;
    for (; j + 4 <= cn; j += 16) {
      int s0 = csr_src[start + j + 0];
      int s1 = csr_src[start + j + 1];
      int s2 = csr_src[start + j + 2];
      int s3 = csr_src[start + j + 3];
      uint4 u0 = *(const uint4*)(hcol + (size_t)s0 * 64);
      uint4 u1 = *(const uint4*)(hcol + (size_t)s1 * 64);
      uint4 u2 = *(const uint4*)(hcol + (size_t)s2 * 64);
      uint4 u3 = *(const uint4*)(hcol + (size_t)s3 * 64);
      acc_bf8(l0, h0, u0);
      acc_bf8(l1, h1, u1);
      acc_bf8(l2, h2, u2);
      acc_bf8(l3, h3, u3);
    }
    if (j < cn) {  // partial chunk, 1..3 entries
      int rem = cn - j;
      int s0 = csr_src[start + j];
      acc_bf8(l1, h1, *(const uint4*)(hcol + (size_t)s0 * 64));
      if (rem > 1) {
        int s1 = csr_src[start + j + 1];
        acc_bf8(l2, h2, *(const uint4*)(hcol + (size_t)s1 * 64));
      }
      if (rem > 2) {
        int s2 = csr_src[start + j + 2];
        acc_bf8(l3, h3, *(const uint4*)(hcol + (size_t)s2 * 64));
      }
    }
    float4 alo = make_float4((l0.x + l1.x) + (l2.x + l3.x),
                             (l0.y + l1.y) + (l2.y + l3.y),
                             (l0.z + l1.z) + (l2.z + l3.z),
                             (l0.w + l1.w) + (l2.w + l3.w));
    float4 ahi = make_float4((h0.x + h1.x) + (h2.x + h3.x),
                             (h0.y + h1.y) + (h2.y + h3.y),
                             (h0.z + h1.z) + (h2.z + h3.z),
                             (h0.w + h1.w) + (h2.w + h3.w));
    // join the 4 quarter-streams (lane bits 3 and 4)
    alo.x += __shfl_xor(alo.x, 8); alo.y += __shfl_xor(alo.y, 8);
    alo.z += __shfl_xor(alo.z, 8); alo.w += __shfl_xor(alo.w, 8);
    ahi.x += __shfl_xor(ahi.x, 8); ahi.y += __shfl_xor(ahi.y, 8);
    ahi.z += __shfl_xor(ahi.z, 8); ahi.w += __shfl_xor(ahi.w, 8);
    alo.x += __shfl_xor(alo.x, 16); alo.y += __shfl_xor(alo.y, 16);
    alo.z += __shfl_xor(alo.z, 16); alo.w += __shfl_xor(alo.w, 16);
    ahi.x += __shfl_xor(ahi.x, 16); ahi.y += __shfl_xor(ahi.y, 16);
    ahi.z += __shfl_xor(ahi.z, 16); ahi.w += __shfl_xor(ahi.w, 16);
    dnode = dinv[node];
    if (quarter == 0) {
      float4 blo = *(const float4*)(bias + c8);
      float4 bhi = *(const float4*)(bias + c8 + 4);
      float4 vlo = make_float4(fmaxf(fmaf(dnode, alo.x, blo.x), 0.f),
                               fmaxf(fmaf(dnode, alo.y, blo.y), 0.f),
                               fmaxf(fmaf(dnode, alo.z, blo.z), 0.f),
                               fmaxf(fmaf(dnode, alo.w, blo.w), 0.f));
      float4 vhi = make_float4(fmaxf(fmaf(dnode, ahi.x, bhi.x), 0.f),
                               fmaxf(fmaf(dnode, ahi.y, bhi.y), 0.f),
                               fmaxf(fmaf(dnode, ahi.z, bhi.z), 0.f),
                               fmaxf(fmaf(dnode, ahi.w, bhi.w), 0.f));
      *(float4*)(&vrow[g][c8]) = vlo;
      *(float4*)(&vrow[g][c8 + 4]) = vhi;
    }
  }
  // gemm phase: 32 lanes/node x 2 cols, wave-internal LDS (no barrier).
  if (valid) {
    const int cc = lane32 * 2;
    float ax = 0.f, ay = 0.f;
#pragma unroll
    for (int k = 0; k < 64; k += 4) {
      float4 rv = *(const float4*)(&vrow[g][k]);
      float2 w0 = *(const float2*)(Ws + (k + 0) * 64 + cc);
      float2 w1 = *(const float2*)(Ws + (k + 1) * 64 + cc);
      float2 w2 = *(const float2*)(Ws + (k + 2) * 64 + cc);
      float2 w3 = *(const float2*)(Ws + (k + 3) * 64 + cc);
      ax = fmaf(rv.x, w0.x, ax); ay = fmaf(rv.x, w0.y, ay);
      ax = fmaf(rv.y, w1.x, ax); ay = fmaf(rv.y, w1.y, ay);
      ax = fmaf(rv.z, w2.x, ax); ay = fmaf(rv.z, w2.y, ay);
      ax = fmaf(rv.w, w3.x, ax); ay = fmaf(rv.w, w3.y, ay);
    }
    unsigned int packed = bf16r(dnode * ax) | (bf16r(dnode * ay) << 16);
    *(unsigned int*)(hout + (size_t)node * 64 + cc) = packed;
  }
}

// Fused layer 2->3: agg (64, relu, b) -> gemm (64->32) -> bf16.
// 8 lanes/node, 32 nodes/block, x4-unrolled gather. [R7/R10 form]
__global__ __launch_bounds__(BLOCK) void fused_agg_gemm32(
    const unsigned short* __restrict__ hin, const int* __restrict__ csr_src,
    const int* __restrict__ offs, const int* __restrict__ cnt,
    const float* __restrict__ dinv, const float* __restrict__ bias,
    const float* __restrict__ Wn, unsigned short* __restrict__ hout, int n) {
  __shared__ float Ws[64 * 32];
  __shared__ float vrow[32][68];  // +4 pad
  for (int i = threadIdx.x * 4; i < 64 * 32; i += BLOCK * 4)
    *(float4*)(Ws + i) = *(const float4*)(Wn + i);
  __syncthreads();
  const int g = threadIdx.x >> 3;
  const int lane8 = threadIdx.x & 7;
  const int c8 = lane8 * 8;
  const int node = blockIdx.x * 32 + g;
  const bool valid = node < n;
  float dnode = 0.f;
  if (valid) {
    const int start = offs[node];
    const int cn = cnt[node];
    const unsigned short* hcol = hin + c8;
    float4 l0 = make_float4(0.f, 0.f, 0.f, 0.f), h0 = l0;
    float4 l1 = l0, h1 = l0, l2 = l0, h2 = l0, l3 = l0, h3 = l0;
    acc_bf8(l0, h0, *(const uint4*)(hcol + (size_t)node * 64));
    int j = 0;
    for (; j + 4 <= cn; j += 4) {
      int s0 = csr_src[start + j + 0];
      int s1 = csr_src[start + j + 1];
      int s2 = csr_src[start + j + 2];
      int s3 = csr_src[start + j + 3];
      uint4 u0 = *(const uint4*)(hcol + (size_t)s0 * 64);
      uint4 u1 = *(const uint4*)(hcol + (size_t)s1 * 64);
      uint4 u2 = *(const uint4*)(hcol + (size_t)s2 * 64);
      uint4 u3 = *(const uint4*)(hcol + (size_t)s3 * 64);
      acc_bf8(l0, h0, u0);
      acc_bf8(l1, h1, u1);
      acc_bf8(l2, h2, u2);
      acc_bf8(l3, h3, u3);
    }
    if (j + 2 <= cn) {
      int s0 = csr_src[start + j + 0];
      int s1 = csr_src[start + j + 1];
      uint4 u0 = *(const uint4*)(hcol + (size_t)s0 * 64);
      uint4 u1 = *(const uint4*)(hcol + (size_t)s1 * 64);
      acc_bf8(l1, h1, u0);
      acc_bf8(l2, h2, u1);
      j += 2;
    }
    if (j < cn) {
      int s0 = csr_src[start + j];
      acc_bf8(l3, h3, *(const uint4*)(hcol + (size_t)s0 * 64));
    }
    float4 alo = make_float4((l0.x + l1.x) + (l2.x + l3.x),
                             (l0.y + l1.y) + (l2.y + l3.y),
                             (l0.z + l1.z) + (l2.z + l3.z),
                             (l0.w + l1.w) + (l2.w + l3.w));
    float4 ahi = make_float4((h0.x + h1.x) + (h2.x + h3.x),
                             (h0.y + h1.y) + (h2.y + h3.y),
                             (h0.z + h1.z) + (h2.z + h3.z),
                             (h0.w + h1.w) + (h2.w + h3.w));
    dnode = dinv[node];
    float4 blo = *(const float4*)(bias + c8);
    float4 bhi = *(const float4*)(bias + c8 + 4);
    float4 vlo = make_float4(fmaxf(fmaf(dnode, alo.x, blo.x), 0.f),
                             fmaxf(fmaf(dnode, alo.y, blo.y), 0.f),
                             fmaxf(fmaf(dnode, alo.z, blo.z), 0.f),
                             fmaxf(fmaf(dnode, alo.w, blo.w), 0.f));
    float4 vhi = make_float4(fmaxf(fmaf(dnode, ahi.x, bhi.x), 0.f),
                             fmaxf(fmaf(dnode, ahi.y, bhi.y), 0.f),
                             fmaxf(fmaf(dnode, ahi.z, bhi.z), 0.f),
                             fmaxf(fmaf(dnode, ahi.w, bhi.w), 0.f));
    *(float4*)(&vrow[g][c8]) = vlo;
    *(float4*)(&vrow[g][c8 + 4]) = vhi;
  }
  if (valid) {
    const int cc = lane8 * 4;
    float4 a0 = make_float4(0.f, 0.f, 0.f, 0.f);
#pragma unroll
    for (int k = 0; k < 64; k += 4) {
      float4 rv = *(const float4*)(&vrow[g][k]);
      a0 = fma4(rv.x, *(const float4*)(Ws + (k + 0) * 32 + cc), a0);
      a0 = fma4(rv.y, *(const float4*)(Ws + (k + 1) * 32 + cc), a0);
      a0 = fma4(rv.z, *(const float4*)(Ws + (k + 2) * 32 + cc), a0);
      a0 = fma4(rv.w, *(const float4*)(Ws + (k + 3) * 32 + cc), a0);
    }
    uint2 packed;
    packed.x = bf16r(dnode * a0.x) | (bf16r(dnode * a0.y) << 16);
    packed.y = bf16r(dnode * a0.z) | (bf16r(dnode * a0.w) << 16);
    *(uint2*)(hout + (size_t)node * 32 + cc) = packed;
  }
}

// Final aggregation (F=32, no relu): 4 lanes/node, 64 nodes/block. [R7 form]
__global__ __launch_bounds__(BLOCK) void agg3_kernel(
    const unsigned short* __restrict__ hbf, const int* __restrict__ csr_src,
    const int* __restrict__ offs, const int* __restrict__ cnt,
    const float* __restrict__ dinv, const float* __restrict__ bias,
    float* __restrict__ out, int n) {
  constexpr int F = 32;
  const int node = blockIdx.x * 64 + (int)(threadIdx.x >> 2);
  const int c8 = (threadIdx.x & 3) * 8;
  if (node >= n) return;
  const int start = offs[node];
  const int cn = cnt[node];
  const unsigned short* hcol = hbf + c8;
  float4 l0 = make_float4(0.f, 0.f, 0.f, 0.f), h0 = l0;
  float4 l1 = l0, h1 = l0, l2 = l0, h2 = l0, l3 = l0, h3 = l0;
  acc_bf8(l0, h0, *(const uint4*)(hcol + (size_t)node * F));
  int j = 0;
  for (; j + 4 <= cn; j += 4) {
    int s0 = csr_src[start + j + 0];
    int s1 = csr_src[start + j + 1];
    int s2 = csr_src[start + j + 2];
    int s3 = csr_src[start + j + 3];
    uint4 u0 = *(const uint4*)(hcol + (size_t)s0 * F);
    uint4 u1 = *(const uint4*)(hcol + (size_t)s1 * F);
    uint4 u2 = *(const uint4*)(hcol + (size_t)s2 * F);
    uint4 u3 = *(const uint4*)(hcol + (size_t)s3 * F);
    acc_bf8(l0, h0, u0);
    acc_bf8(l1, h1, u1);
    acc_bf8(l2, h2, u2);
    acc_bf8(l3, h3, u3);
  }
  if (j + 2 <= cn) {
    int s0 = csr_src[start + j + 0];
    int s1 = csr_src[start + j + 1];
    uint4 u0 = *(const uint4*)(hcol + (size_t)s0 * F);
    uint4 u1 = *(const uint4*)(hcol + (size_t)s1 * F);
    acc_bf8(l1, h1, u0);
    acc_bf8(l2, h2, u1);
    j += 2;
  }
  if (j < cn) {
    int s0 = csr_src[start + j];
    acc_bf8(l3, h3, *(const uint4*)(hcol + (size_t)s0 * F));
  }
  float4 alo = make_float4((l0.x + l1.x) + (l2.x + l3.x),
                           (l0.y + l1.y) + (l2.y + l3.y),
                           (l0.z + l1.z) + (l2.z + l3.z),
                           (l0.w + l1.w) + (l2.w + l3.w));
  float4 ahi = make_float4((h0.x + h1.x) + (h2.x + h3.x),
                           (h0.y + h1.y) + (h2.y + h3.y),
                           (h0.z + h1.z) + (h2.z + h3.z),
                           (h0.w + h1.w) + (h2.w + h3.w));
  float d = dinv[node];
  float4 blo = *(const float4*)(bias + c8);
  float4 bhi = *(const float4*)(bias + c8 + 4);
  f32x4 vlo = {fmaf(d, alo.x, blo.x), fmaf(d, alo.y, blo.y),
               fmaf(d, alo.z, blo.z), fmaf(d, alo.w, blo.w)};
  f32x4 vhi = {fmaf(d, ahi.x, bhi.x), fmaf(d, ahi.y, bhi.y),
               fmaf(d, ahi.z, bhi.z), fmaf(d, ahi.w, bhi.w)};
  float* op = out + (size_t)node * F + c8;
  __builtin_nontemporal_store(vlo, (f32x4*)op);
  __builtin_nontemporal_store(vhi, (f32x4*)(op + 4));
}

static inline size_t align_up(size_t v, size_t a) { return (v + a - 1) & ~(a - 1); }

extern "C" void kernel_launch(void* const* d_in, const int* in_sizes, int n_in,
                              void* d_out, int out_size, void* d_ws, size_t ws_size,
                              hipStream_t stream) {
  const float* x = (const float*)d_in[0];
  const int* edge_index = (const int*)d_in[1];
  const float* W1 = (const float*)d_in[2];
  const float* b1 = (const float*)d_in[3];
  const float* W2 = (const float*)d_in[4];
  const float* b2 = (const float*)d_in[5];
  const float* W3 = (const float*)d_in[6];
  const float* b3 = (const float*)d_in[7];
  float* out = (float*)d_out;

  const int n = in_sizes[0] / 64;       // 100000
  const int e = in_sizes[1] / 2;        // 1600000
  const int* e_src = edge_index;
  const int* e_dst = edge_index + e;
  const int npb = (n + NBUCKET - 1) / NBUCKET;  // 196

  char* ws = (char*)d_ws;
  size_t off = 0;
  int* bcursor = (int*)(ws + off); off = align_up(off + NBUCKET * 4, 512);
  int* offs    = (int*)(ws + off); off = align_up(off + (size_t)n * 4, 512);
  int* cnt     = (int*)(ws + off); off = align_up(off + (size_t)n * 4, 512);
  float* dinv  = (float*)(ws + off); off = align_up(off + (size_t)n * 4, 512);
  int* binned  = (int*)(ws + off); off = align_up(off + (size_t)NBUCKET * SLOT * 4, 512);
  int* csr_src = (int*)(ws + off); off = align_up(off + (size_t)NBUCKET * SLOT * 4, 512);
  unsigned short* hbuf_a = (unsigned short*)(ws + off);
  off = align_up(off + (size_t)n * 64 * 2, 512);
  unsigned short* hbuf_b = (unsigned short*)(ws + off);
  off = align_up(off + (size_t)n * 64 * 2, 512);
  (void)ws_size;

  const int gC = (e + CHUNK - 1) / CHUNK;

  hipMemsetAsync(bcursor, 0, NBUCKET * 4, stream);
  binning_kernel<<<gC, BLOCK, 0, stream>>>(e_src, e_dst, bcursor, binned, e, npb);
  bucket_build<<<NBUCKET, BLOCK, 0, stream>>>(binned, bcursor, offs, cnt, dinv,
                                              csr_src, n, npb);

  gemm1_kernel<<<(n + 15) / 16, BLOCK, 0, stream>>>(x, W1, dinv, hbuf_a, n);
  fused_agg_gemm64<<<(n + 7) / 8, BLOCK, 0, stream>>>(
      hbuf_a, csr_src, offs, cnt, dinv, b1, W2, hbuf_b, n);
  fused_agg_gemm32<<<(n + 31) / 32, BLOCK, 0, stream>>>(
      hbuf_b, csr_src, offs, cnt, dinv, b2, W3, hbuf_a, n);
  agg3_kernel<<<(n + 63) / 64, BLOCK, 0, stream>>>(hbuf_a, csr_src, offs, cnt,
                                                   dinv, b3, out, n);
}

// Round 13
// 248.774 us; speedup vs baseline: 1.1120x; 1.1120x over previous
//
#include <hip/hip_runtime.h>
#include <hip/hip_bf16.h>

// GCN 3-layer forward on MI355X.  (R10 best-known config, restored)
// h' = bf16( dinv .* (x @ W) );  out = relu(dinv .* (h'[i]+sum h'[src]) + b)
// CSR via single-pass bucket binning (arena slots).
// fused64: 16 lanes/node (8 col-lanes x 2 neighbor-halves, shfl_xor join).
// fused32/agg3: 8(4) lanes/node, x4-unrolled gather.
// Measured split-ladder for fused64 gather: 8-lane=56us, 16-lane=49us,
// 32-lane=71us -> 16 is the optimum. Panel/XCD-sliced layouts regress
// (R9: gemm VGPR+write-amp blowup). 4-row gemm blocking regresses (R6).

#define BLOCK 256
#define NBUCKET 512
#define CHUNK 4096
#define SLOT 4608
#define MAX_NPB 256

typedef float f32x4 __attribute__((ext_vector_type(4)));

__device__ __forceinline__ float4 fma4(float s, float4 a, float4 b) {
  return make_float4(fmaf(s, a.x, b.x), fmaf(s, a.y, b.y),
                     fmaf(s, a.z, b.z), fmaf(s, a.w, b.w));
}

__device__ __forceinline__ unsigned int bf16r(float f) {
  unsigned int u = __float_as_uint(f);
  u += 0x7fffu + ((u >> 16) & 1u);
  return u >> 16;
}

__device__ __forceinline__ void acc_bf8(float4& lo, float4& hi, uint4 u) {
  lo.x += __uint_as_float(u.x << 16);
  lo.y += __uint_as_float(u.x & 0xffff0000u);
  lo.z += __uint_as_float(u.y << 16);
  lo.w += __uint_as_float(u.y & 0xffff0000u);
  hi.x += __uint_as_float(u.z << 16);
  hi.y += __uint_as_float(u.z & 0xffff0000u);
  hi.z += __uint_as_float(u.w << 16);
  hi.w += __uint_as_float(u.w & 0xffff0000u);
}

// ---- CSR build ----

__global__ __launch_bounds__(BLOCK) void binning_kernel(
    const int* __restrict__ src, const int* __restrict__ dst,
    int* __restrict__ bcursor, int* __restrict__ binned, int e, int npb) {
  __shared__ int h[NBUCKET];
  __shared__ int base[NBUCKET];
  for (int i = threadIdx.x; i < NBUCKET; i += BLOCK) h[i] = 0;
  __syncthreads();
  const int cbase = blockIdx.x * CHUNK;
#pragma unroll
  for (int k = 0; k < CHUNK; k += BLOCK * 4) {
    int i = cbase + k + threadIdx.x * 4;
    if (i + 3 < e) {
      int4 d4 = *(const int4*)(dst + i);
      atomicAdd(&h[d4.x / npb], 1);
      atomicAdd(&h[d4.y / npb], 1);
      atomicAdd(&h[d4.z / npb], 1);
      atomicAdd(&h[d4.w / npb], 1);
    } else {
      for (int t = 0; t < 4; ++t)
        if (i + t < e) atomicAdd(&h[dst[i + t] / npb], 1);
    }
  }
  __syncthreads();
  for (int i = threadIdx.x; i < NBUCKET; i += BLOCK) {
    int c = h[i];
    base[i] = c ? atomicAdd(&bcursor[i], c) : 0;
    h[i] = 0;
  }
  __syncthreads();
#pragma unroll
  for (int k = 0; k < CHUNK; k += BLOCK * 4) {
    int i = cbase + k + threadIdx.x * 4;
    if (i + 3 < e) {
      int4 d4 = *(const int4*)(dst + i);
      int4 s4 = *(const int4*)(src + i);
      int b0 = d4.x / npb, b1 = d4.y / npb, b2 = d4.z / npb, b3 = d4.w / npb;
      int o0 = atomicAdd(&h[b0], 1);
      int o1 = atomicAdd(&h[b1], 1);
      int o2 = atomicAdd(&h[b2], 1);
      int o3 = atomicAdd(&h[b3], 1);
      binned[b0 * SLOT + base[b0] + o0] = s4.x | ((d4.x - b0 * npb) << 17);
      binned[b1 * SLOT + base[b1] + o1] = s4.y | ((d4.y - b1 * npb) << 17);
      binned[b2 * SLOT + base[b2] + o2] = s4.z | ((d4.z - b2 * npb) << 17);
      binned[b3 * SLOT + base[b3] + o3] = s4.w | ((d4.w - b3 * npb) << 17);
    } else {
      for (int t = 0; t < 4; ++t) {
        if (i + t < e) {
          int d = dst[i + t];
          int bkt = d / npb;
          int lofs = atomicAdd(&h[bkt], 1);
          binned[bkt * SLOT + base[bkt] + lofs] =
              src[i + t] | ((d - bkt * npb) << 17);
        }
      }
    }
  }
}

__global__ __launch_bounds__(BLOCK) void bucket_build(
    const int* __restrict__ binned, const int* __restrict__ bcursor,
    int* __restrict__ offs, int* __restrict__ cnt, float* __restrict__ dinv,
    int* __restrict__ csr_src, int n, int npb) {
  __shared__ int nhist[MAX_NPB];
  __shared__ int noff[MAX_NPB];
  __shared__ int lcsr[SLOT];
  const int b = blockIdx.x;
  const int node_base = b * npb;
  const int nodes = min(npb, n - node_base);
  if (nodes <= 0) return;
  const int ebase = b * SLOT;
  const int ecnt = bcursor[b];
  for (int i = threadIdx.x; i < npb; i += BLOCK) nhist[i] = 0;
  __syncthreads();
  for (int i = threadIdx.x; i < ecnt; i += BLOCK)
    atomicAdd(&nhist[binned[ebase + i] >> 17], 1);
  __syncthreads();
  if (threadIdx.x < 64) {
    const int lane = threadIdx.x;
    const int bi = lane * 4;
    int v0 = (bi + 0 < nodes) ? nhist[bi + 0] : 0;
    int v1 = (bi + 1 < nodes) ? nhist[bi + 1] : 0;
    int v2 = (bi + 2 < nodes) ? nhist[bi + 2] : 0;
    int v3 = (bi + 3 < nodes) ? nhist[bi + 3] : 0;
    int tsum = v0 + v1 + v2 + v3;
    int s = tsum;
#pragma unroll
    for (int o = 1; o < 64; o <<= 1) {
      int u = __shfl_up(s, o, 64);
      if (lane >= o) s += u;
    }
    int texcl = s - tsum;
    if (bi + 0 < nodes) noff[bi + 0] = texcl;
    if (bi + 1 < nodes) noff[bi + 1] = texcl + v0;
    if (bi + 2 < nodes) noff[bi + 2] = texcl + v0 + v1;
    if (bi + 3 < nodes) noff[bi + 3] = texcl + v0 + v1 + v2;
  }
  __syncthreads();
  for (int i = threadIdx.x; i < nodes; i += BLOCK) {
    int c = nhist[i];
    offs[node_base + i] = ebase + noff[i];
    cnt[node_base + i] = c;
    dinv[node_base + i] = rsqrtf((float)(c + 1));
  }
  __syncthreads();
  for (int i = threadIdx.x; i < ecnt; i += BLOCK) {
    int v = binned[ebase + i];
    int pos = atomicAdd(&noff[v >> 17], 1);
    lcsr[pos] = v & 0x1ffff;
  }
  __syncthreads();
  for (int i = threadIdx.x; i < ecnt; i += BLOCK)
    csr_src[ebase + i] = lcsr[i];
}

// ---- dense layers ----

// Layer-1 GEMM: 1 row x 4 cols/thread, W in LDS.
__global__ __launch_bounds__(BLOCK) void gemm1_kernel(
    const float* __restrict__ x, const float* __restrict__ W,
    const float* __restrict__ dinv, unsigned short* __restrict__ hbf, int n) {
  __shared__ float Ws[64 * 64];
  for (int i = threadIdx.x * 4; i < 64 * 64; i += BLOCK * 4)
    *(float4*)(Ws + i) = *(const float4*)(W + i);
  __syncthreads();
  const int row = blockIdx.x * 16 + (int)(threadIdx.x >> 4);
  const int c4 = (threadIdx.x & 15) * 4;
  if (row >= n) return;
  const float* xr = x + (size_t)row * 64;
  float4 acc = make_float4(0.f, 0.f, 0.f, 0.f);
#pragma unroll
  for (int k = 0; k < 64; k += 4) {
    f32x4 xn = __builtin_nontemporal_load((const f32x4*)(xr + k));
    float4 w0 = *(const float4*)(Ws + (k + 0) * 64 + c4);
    float4 w1 = *(const float4*)(Ws + (k + 1) * 64 + c4);
    float4 w2 = *(const float4*)(Ws + (k + 2) * 64 + c4);
    float4 w3 = *(const float4*)(Ws + (k + 3) * 64 + c4);
    acc = fma4(xn.x, w0, acc);
    acc = fma4(xn.y, w1, acc);
    acc = fma4(xn.z, w2, acc);
    acc = fma4(xn.w, w3, acc);
  }
  float d = dinv[row];
  uint2 packed;
  packed.x = bf16r(d * acc.x) | (bf16r(d * acc.y) << 16);
  packed.y = bf16r(d * acc.z) | (bf16r(d * acc.w) << 16);
  *(uint2*)(hbf + (size_t)row * 64 + c4) = packed;
}

// Fused layer 1->2: agg (64, relu, b) -> gemm (64->64) -> bf16.
// 16 lanes/node = 8 col-lanes x 2 neighbor-halves; 16 nodes/block.
__global__ __launch_bounds__(BLOCK) void fused_agg_gemm64(
    const unsigned short* __restrict__ hin, const int* __restrict__ csr_src,
    const int* __restrict__ offs, const int* __restrict__ cnt,
    const float* __restrict__ dinv, const float* __restrict__ bias,
    const float* __restrict__ Wn, unsigned short* __restrict__ hout, int n) {
  __shared__ float Ws[64 * 64];
  __shared__ float vrow[16][68];  // +4 pad
  for (int i = threadIdx.x * 4; i < 64 * 64; i += BLOCK * 4)
    *(float4*)(Ws + i) = *(const float4*)(Wn + i);
  __syncthreads();
  const int g = threadIdx.x >> 4;
  const int lane16 = threadIdx.x & 15;
  const int colgrp = lane16 & 7;
  const int half = lane16 >> 3;
  const int c8 = colgrp * 8;
  const int node = blockIdx.x * 16 + g;
  const bool valid = node < n;
  float dnode = 0.f;
  if (valid) {
    const int start = offs[node];
    const int cn = cnt[node];
    const unsigned short* hcol = hin + c8;
    float4 l0 = make_float4(0.f, 0.f, 0.f, 0.f), h0 = l0;
    float4 l1 = l0, h1 = l0, l2 = l0, h2 = l0, l3 = l0, h3 = l0;
    if (half == 0)
      acc_bf8(l0, h0, *(const uint4*)(hcol + (size_t)node * 64));  // self
    int j = half * 4;
    for (; j + 4 <= cn; j += 8) {
      int s0 = csr_src[start + j + 0];
      int s1 = csr_src[start + j + 1];
      int s2 = csr_src[start + j + 2];
      int s3 = csr_src[start + j + 3];
      uint4 u0 = *(const uint4*)(hcol + (size_t)s0 * 64);
      uint4 u1 = *(const uint4*)(hcol + (size_t)s1 * 64);
      uint4 u2 = *(const uint4*)(hcol + (size_t)s2 * 64);
      uint4 u3 = *(const uint4*)(hcol + (size_t)s3 * 64);
      acc_bf8(l0, h0, u0);
      acc_bf8(l1, h1, u1);
      acc_bf8(l2, h2, u2);
      acc_bf8(l3, h3, u3);
    }
    if (j < cn) {  // partial chunk, at most 3 entries
      int rem = cn - j;
      int s0 = csr_src[start + j];
      acc_bf8(l1, h1, *(const uint4*)(hcol + (size_t)s0 * 64));
      if (rem > 1) {
        int s1 = csr_src[start + j + 1];
        acc_bf8(l2, h2, *(const uint4*)(hcol + (size_t)s1 * 64));
      }
      if (rem > 2) {
        int s2 = csr_src[start + j + 2];
        acc_bf8(l3, h3, *(const uint4*)(hcol + (size_t)s2 * 64));
      }
    }
    float4 alo = make_float4((l0.x + l1.x) + (l2.x + l3.x),
                             (l0.y + l1.y) + (l2.y + l3.y),
                             (l0.z + l1.z) + (l2.z + l3.z),
                             (l0.w + l1.w) + (l2.w + l3.w));
    float4 ahi = make_float4((h0.x + h1.x) + (h2.x + h3.x),
                             (h0.y + h1.y) + (h2.y + h3.y),
                             (h0.z + h1.z) + (h2.z + h3.z),
                             (h0.w + h1.w) + (h2.w + h3.w));
    alo.x += __shfl_xor(alo.x, 8); alo.y += __shfl_xor(alo.y, 8);
    alo.z += __shfl_xor(alo.z, 8); alo.w += __shfl_xor(alo.w, 8);
    ahi.x += __shfl_xor(ahi.x, 8); ahi.y += __shfl_xor(ahi.y, 8);
    ahi.z += __shfl_xor(ahi.z, 8); ahi.w += __shfl_xor(ahi.w, 8);
    dnode = dinv[node];
    if (half == 0) {
      float4 blo = *(const float4*)(bias + c8);
      float4 bhi = *(const float4*)(bias + c8 + 4);
      float4 vlo = make_float4(fmaxf(fmaf(dnode, alo.x, blo.x), 0.f),
                               fmaxf(fmaf(dnode, alo.y, blo.y), 0.f),
                               fmaxf(fmaf(dnode, alo.z, blo.z), 0.f),
                               fmaxf(fmaf(dnode, alo.w, blo.w), 0.f));
      float4 vhi = make_float4(fmaxf(fmaf(dnode, ahi.x, bhi.x), 0.f),
                               fmaxf(fmaf(dnode, ahi.y, bhi.y), 0.f),
                               fmaxf(fmaf(dnode, ahi.z, bhi.z), 0.f),
                               fmaxf(fmaf(dnode, ahi.w, bhi.w), 0.f));
      *(float4*)(&vrow[g][c8]) = vlo;
      *(float4*)(&vrow[g][c8 + 4]) = vhi;
    }
  }
  if (valid) {
    const int cc = lane16 * 4;
    float4 a0 = make_float4(0.f, 0.f, 0.f, 0.f);
#pragma unroll
    for (int k = 0; k < 64; k += 4) {
      float4 rv = *(const float4*)(&vrow[g][k]);
      a0 = fma4(rv.x, *(const float4*)(Ws + (k + 0) * 64 + cc), a0);
      a0 = fma4(rv.y, *(const float4*)(Ws + (k + 1) * 64 + cc), a0);
      a0 = fma4(rv.z, *(const float4*)(Ws + (k + 2) * 64 + cc), a0);
      a0 = fma4(rv.w, *(const float4*)(Ws + (k + 3) * 64 + cc), a0);
    }
    uint2 packed;
    packed.x = bf16r(dnode * a0.x) | (bf16r(dnode * a0.y) << 16);
    packed.y = bf16r(dnode * a0.z) | (bf16r(dnode * a0.w) << 16);
    *(uint2*)(hout + (size_t)node * 64 + cc) = packed;
  }
}

// Fused layer 2->3: agg (64, relu, b) -> gemm (64->32) -> bf16.
// 8 lanes/node, 32 nodes/block, x4-unrolled gather.
__global__ __launch_bounds__(BLOCK) void fused_agg_gemm32(
    const unsigned short* __restrict__ hin, const int* __restrict__ csr_src,
    const int* __restrict__ offs, const int* __restrict__ cnt,
    const float* __restrict__ dinv, const float* __restrict__ bias,
    const float* __restrict__ Wn, unsigned short* __restrict__ hout, int n) {
  __shared__ float Ws[64 * 32];
  __shared__ float vrow[32][68];  // +4 pad
  for (int i = threadIdx.x * 4; i < 64 * 32; i += BLOCK * 4)
    *(float4*)(Ws + i) = *(const float4*)(Wn + i);
  __syncthreads();
  const int g = threadIdx.x >> 3;
  const int lane8 = threadIdx.x & 7;
  const int c8 = lane8 * 8;
  const int node = blockIdx.x * 32 + g;
  const bool valid = node < n;
  float dnode = 0.f;
  if (valid) {
    const int start = offs[node];
    const int cn = cnt[node];
    const unsigned short* hcol = hin + c8;
    float4 l0 = make_float4(0.f, 0.f, 0.f, 0.f), h0 = l0;
    float4 l1 = l0, h1 = l0, l2 = l0, h2 = l0, l3 = l0, h3 = l0;
    acc_bf8(l0, h0, *(const uint4*)(hcol + (size_t)node * 64));
    int j = 0;
    for (; j + 4 <= cn; j += 4) {
      int s0 = csr_src[start + j + 0];
      int s1 = csr_src[start + j + 1];
      int s2 = csr_src[start + j + 2];
      int s3 = csr_src[start + j + 3];
      uint4 u0 = *(const uint4*)(hcol + (size_t)s0 * 64);
      uint4 u1 = *(const uint4*)(hcol + (size_t)s1 * 64);
      uint4 u2 = *(const uint4*)(hcol + (size_t)s2 * 64);
      uint4 u3 = *(const uint4*)(hcol + (size_t)s3 * 64);
      acc_bf8(l0, h0, u0);
      acc_bf8(l1, h1, u1);
      acc_bf8(l2, h2, u2);
      acc_bf8(l3, h3, u3);
    }
    if (j + 2 <= cn) {
      int s0 = csr_src[start + j + 0];
      int s1 = csr_src[start + j + 1];
      uint4 u0 = *(const uint4*)(hcol + (size_t)s0 * 64);
      uint4 u1 = *(const uint4*)(hcol + (size_t)s1 * 64);
      acc_bf8(l1, h1, u0);
      acc_bf8(l2, h2, u1);
      j += 2;
    }
    if (j < cn) {
      int s0 = csr_src[start + j];
      acc_bf8(l3, h3, *(const uint4*)(hcol + (size_t)s0 * 64));
    }
    float4 alo = make_float4((l0.x + l1.x) + (l2.x + l3.x),
                             (l0.y + l1.y) + (l2.y + l3.y),
                             (l0.z + l1.z) + (l2.z + l3.z),
                             (l0.w + l1.w) + (l2.w + l3.w));
    float4 ahi = make_float4((h0.x + h1.x) + (h2.x + h3.x),
                             (h0.y + h1.y) + (h2.y + h3.y),
                             (h0.z + h1.z) + (h2.z + h3.z),
                             (h0.w + h1.w) + (h2.w + h3.w));
    dnode = dinv[node];
    float4 blo = *(const float4*)(bias + c8);
    float4 bhi = *(const float4*)(bias + c8 + 4);
    float4 vlo = make_float4(fmaxf(fmaf(dnode, alo.x, blo.x), 0.f),
                             fmaxf(fmaf(dnode, alo.y, blo.y), 0.f),
                             fmaxf(fmaf(dnode, alo.z, blo.z), 0.f),
                             fmaxf(fmaf(dnode, alo.w, blo.w), 0.f));
    float4 vhi = make_float4(fmaxf(fmaf(dnode, ahi.x, bhi.x), 0.f),
                             fmaxf(fmaf(dnode, ahi.y, bhi.y), 0.f),
                             fmaxf(fmaf(dnode, ahi.z, bhi.z), 0.f),
                             fmaxf(fmaf(dnode, ahi.w, bhi.w), 0.f));
    *(float4*)(&vrow[g][c8]) = vlo;
    *(float4*)(&vrow[g][c8 + 4]) = vhi;
  }
  if (valid) {
    const int cc = lane8 * 4;
    float4 a0 = make_float4(0.f, 0.f, 0.f, 0.f);
#pragma unroll
    for (int k = 0; k < 64; k += 4) {
      float4 rv = *(const float4*)(&vrow[g][k]);
      a0 = fma4(rv.x, *(const float4*)(Ws + (k + 0) * 32 + cc), a0);
      a0 = fma4(rv.y, *(const float4*)(Ws + (k + 1) * 32 + cc), a0);
      a0 = fma4(rv.z, *(const float4*)(Ws + (k + 2) * 32 + cc), a0);
      a0 = fma4(rv.w, *(const float4*)(Ws + (k + 3) * 32 + cc), a0);
    }
    uint2 packed;
    packed.x = bf16r(dnode * a0.x) | (bf16r(dnode * a0.y) << 16);
    packed.y = bf16r(dnode * a0.z) | (bf16r(dnode * a0.w) << 16);
    *(uint2*)(hout + (size_t)node * 32 + cc) = packed;
  }
}

// Final aggregation (F=32, no relu): 4 lanes/node, 64 nodes/block.
__global__ __launch_bounds__(BLOCK) void agg3_kernel(
    const unsigned short* __restrict__ hbf, const int* __restrict__ csr_src,
    const int* __restrict__ offs, const int* __restrict__ cnt,
    const float* __restrict__ dinv, const float* __restrict__ bias,
    float* __restrict__ out, int n) {
  constexpr int F = 32;
  const int node = blockIdx.x * 64 + (int)(threadIdx.x >> 2);
  const int c8 = (threadIdx.x & 3) * 8;
  if (node >= n) return;
  const int start = offs[node];
  const int cn = cnt[node];
  const unsigned short* hcol = hbf + c8;
  float4 l0 = make_float4(0.f, 0.f, 0.f, 0.f), h0 = l0;
  float4 l1 = l0, h1 = l0, l2 = l0, h2 = l0, l3 = l0, h3 = l0;
  acc_bf8(l0, h0, *(const uint4*)(hcol + (size_t)node * F));
  int j = 0;
  for (; j + 4 <= cn; j += 4) {
    int s0 = csr_src[start + j + 0];
    int s1 = csr_src[start + j + 1];
    int s2 = csr_src[start + j + 2];
    int s3 = csr_src[start + j + 3];
    uint4 u0 = *(const uint4*)(hcol + (size_t)s0 * F);
    uint4 u1 = *(const uint4*)(hcol + (size_t)s1 * F);
    uint4 u2 = *(const uint4*)(hcol + (size_t)s2 * F);
    uint4 u3 = *(const uint4*)(hcol + (size_t)s3 * F);
    acc_bf8(l0, h0, u0);
    acc_bf8(l1, h1, u1);
    acc_bf8(l2, h2, u2);
    acc_bf8(l3, h3, u3);
  }
  if (j + 2 <= cn) {
    int s0 = csr_src[start + j + 0];
    int s1 = csr_src[start + j + 1];
    uint4 u0 = *(const uint4*)(hcol + (size_t)s0 * F);
    uint4 u1 = *(const uint4*)(hcol + (size_t)s1 * F);
    acc_bf8(l1, h1, u0);
    acc_bf8(l2, h2, u1);
    j += 2;
  }
  if (j < cn) {
    int s0 = csr_src[start + j];
    acc_bf8(l3, h3, *(const uint4*)(hcol + (size_t)s0 * F));
  }
  float4 alo = make_float4((l0.x + l1.x) + (l2.x + l3.x),
                           (l0.y + l1.y) + (l2.y + l3.y),
                           (l0.z + l1.z) + (l2.z + l3.z),
                           (l0.w + l1.w) + (l2.w + l3.w));
  float4 ahi = make_float4((h0.x + h1.x) + (h2.x + h3.x),
                           (h0.y + h1.y) + (h2.y + h3.y),
                           (h0.z + h1.z) + (h2.z + h3.z),
                           (h0.w + h1.w) + (h2.w + h3.w));
  float d = dinv[node];
  float4 blo = *(const float4*)(bias + c8);
  float4 bhi = *(const float4*)(bias + c8 + 4);
  f32x4 vlo = {fmaf(d, alo.x, blo.x), fmaf(d, alo.y, blo.y),
               fmaf(d, alo.z, blo.z), fmaf(d, alo.w, blo.w)};
  f32x4 vhi = {fmaf(d, ahi.x, bhi.x), fmaf(d, ahi.y, bhi.y),
               fmaf(d, ahi.z, bhi.z), fmaf(d, ahi.w, bhi.w)};
  float* op = out + (size_t)node * F + c8;
  __builtin_nontemporal_store(vlo, (f32x4*)op);
  __builtin_nontemporal_store(vhi, (f32x4*)(op + 4));
}

static inline size_t align_up(size_t v, size_t a) { return (v + a - 1) & ~(a - 1); }

extern "C" void kernel_launch(void* const* d_in, const int* in_sizes, int n_in,
                              void* d_out, int out_size, void* d_ws, size_t ws_size,
                              hipStream_t stream) {
  const float* x = (const float*)d_in[0];
  const int* edge_index = (const int*)d_in[1];
  const float* W1 = (const float*)d_in[2];
  const float* b1 = (const float*)d_in[3];
  const float* W2 = (const float*)d_in[4];
  const float* b2 = (const float*)d_in[5];
  const float* W3 = (const float*)d_in[6];
  const float* b3 = (const float*)d_in[7];
  float* out = (float*)d_out;

  const int n = in_sizes[0] / 64;       // 100000
  const int e = in_sizes[1] / 2;        // 1600000
  const int* e_src = edge_index;
  const int* e_dst = edge_index + e;
  const int npb = (n + NBUCKET - 1) / NBUCKET;  // 196

  char* ws = (char*)d_ws;
  size_t off = 0;
  int* bcursor = (int*)(ws + off); off = align_up(off + NBUCKET * 4, 512);
  int* offs    = (int*)(ws + off); off = align_up(off + (size_t)n * 4, 512);
  int* cnt     = (int*)(ws + off); off = align_up(off + (size_t)n * 4, 512);
  float* dinv  = (float*)(ws + off); off = align_up(off + (size_t)n * 4, 512);
  int* binned  = (int*)(ws + off); off = align_up(off + (size_t)NBUCKET * SLOT * 4, 512);
  int* csr_src = (int*)(ws + off); off = align_up(off + (size_t)NBUCKET * SLOT * 4, 512);
  unsigned short* hbuf_a = (unsigned short*)(ws + off);
  off = align_up(off + (size_t)n * 64 * 2, 512);
  unsigned short* hbuf_b = (unsigned short*)(ws + off);
  off = align_up(off + (size_t)n * 64 * 2, 512);
  (void)ws_size;

  const int gC = (e + CHUNK - 1) / CHUNK;

  hipMemsetAsync(bcursor, 0, NBUCKET * 4, stream);
  binning_kernel<<<gC, BLOCK, 0, stream>>>(e_src, e_dst, bcursor, binned, e, npb);
  bucket_build<<<NBUCKET, BLOCK, 0, stream>>>(binned, bcursor, offs, cnt, dinv,
                                              csr_src, n, npb);

  gemm1_kernel<<<(n + 15) / 16, BLOCK, 0, stream>>>(x, W1, dinv, hbuf_a, n);
  fused_agg_gemm64<<<(n + 15) / 16, BLOCK, 0, stream>>>(
      hbuf_a, csr_src, offs, cnt, dinv, b1, W2, hbuf_b, n);
  fused_agg_gemm32<<<(n + 31) / 32, BLOCK, 0, stream>>>(
      hbuf_b, csr_src, offs, cnt, dinv, b2, W3, hbuf_a, n);
  agg3_kernel<<<(n + 63) / 64, BLOCK, 0, stream>>>(hbuf_a, csr_src, offs, cnt,
                                                   dinv, b3, out, n);
}